// Round 11
// baseline (67.298 us; speedup 1.0000x reference)
//
#include <hip/hip_runtime.h>

// CorrelationCost (tfa): out[b, dy*9+dx, y, x] =
//   (1/128) * sum_c prv[b,c,y,x] * nxt[b,c,y+dy-4,x+dx-4], zero-padded.
// B=4, C=128, H=128, W=256 -> out [4, 81, 128, 256] fp32.
//
// R10 -> R11: (1) T14 split staging: issue global loads for chunk ck+1 into
// registers, run compute(ck), THEN cvt+ds_write after the barrier -- global
// latency hides under MFMAs instead of serializing in program order.
// Single LDS buffer, 2 barriers/chunk. (2) Row pads (NRS=484, PRS=324,
// both =4 mod 32) spread staging-write banks (was uniform 4-way).
// Compute / epilogue mapping identical to R10 (verified, absmax 2e-3).

#define SR 4
#define ND 9
#define BB 4
#define CC 128
#define HH 128
#define WW 256
#define HW (HH * WW)

#define YT 4          // y rows per block
#define XT 32         // x px per block
#define NR 12         // N rows staged: y0-4 .. y0+7
#define NW 48         // N px staged:  x0-8 .. x0+39
#define STR 10        // u32 stride per px (8 cp + 2 pad)
#define PRS (XT * STR + 4)        // 324 (=4 mod 32)
#define NRS (NW * STR + 4)        // 484 (=4 mod 32)
#define POFF 0
#define NOFF (YT * PRS)           // 1296
#define OLSZ (81 * YT * XT)       // 10368 u32 = 41472 B (epilogue scratch)

typedef __fp16 h2 __attribute__((ext_vector_type(2)));
typedef __fp16 h4 __attribute__((ext_vector_type(4)));
typedef float f32x4 __attribute__((ext_vector_type(4)));

static __device__ __forceinline__ h2 pk(float lo, float hi) {
    return __builtin_amdgcn_cvt_pkrtz(lo, hi);
}
static __device__ __forceinline__ unsigned as_u32(h2 h) {
    union { h2 h; unsigned u; } v; v.h = h; return v.u;
}
static __device__ __forceinline__ h4 as_h4(uint2 u) {
    union { uint2 u; h4 h; } v; v.u = u; return v.h;
}

__global__ __launch_bounds__(512, 4) void costvol_kernel(
    const float* __restrict__ prv,
    const float* __restrict__ nxt,
    float* __restrict__ out)
{
    __shared__ unsigned shraw[OLSZ];   // staging (7104 u32) U epilogue (10368)

    // XCD-chunked bijective swizzle (1024 % 8 == 0).
    const int nwg  = gridDim.x;
    const int cpx  = nwg >> 3;
    const int orig = blockIdx.x;
    const int wid  = (orig & 7) * cpx + (orig >> 3);

    // x-tile fastest: neighbor blocks share N rows in L2.
    const int xt = wid & 7;
    const int yt = (wid >> 3) & 31;
    const int b  = wid >> 8;
    const int x0 = xt << 5;
    const int y0 = yt << 2;

    const int tid  = threadIdx.x;
    const int w    = tid >> 6;
    const int lane = tid & 63;
    const int li   = lane & 15;
    const int kg   = lane >> 4;          // k-group 0..3
    const int koff = kg << 1;            // u32 offset of this lane's 4 halves

    const int y2 = w & 1;                // y-pair
    const int s  = (w >> 1) & 1;         // A subtile (16 px)
    const int g  = w >> 2;               // B tile parity
    const int ts = s + g;                // B tile index 0..2

    // ---- staging role descriptors (wave-uniform branch: waves 0..5 = N) ----
    const int n_cp = tid & 7;
    const int n_u  = tid >> 3;           // 0..47 (N group)
    const int n_q  = n_u >> 2;           // 0..11
    const int n_rb = n_u & 3;
    const int n_xg = x0 - 8 + (n_q << 2);
    const bool n_xok = (n_xg >= 0) && (n_xg + 3 < WW);

    const int pt   = tid - 384;
    const int p_cp = pt & 7;
    const int p_v  = pt >> 3;            // 0..15
    const int p_y  = p_v & 3;
    const int p_qb = p_v >> 2;           // 0..3

    float4 rlo[3], rhi[3];

    auto issue = [&](int ck) {
        const int c0 = ck << 4;
        if (tid < 384) {
            const float* bp = nxt + (size_t)(b * CC + c0 + 2 * n_cp) * HW + n_xg;
            #pragma unroll
            for (int it = 0; it < 3; ++it) {
                const int rg = y0 + n_rb + (it << 2) - SR;
                if (n_xok && (unsigned)rg < (unsigned)HH) {
                    const float* sr = bp + (size_t)rg * WW;
                    rlo[it] = *(const float4*)sr;
                    rhi[it] = *(const float4*)(sr + HW);
                } else {
                    rlo[it] = make_float4(0.f, 0.f, 0.f, 0.f);
                    rhi[it] = make_float4(0.f, 0.f, 0.f, 0.f);
                }
            }
        } else {
            const float* sp = prv + (size_t)(b * CC + c0 + 2 * p_cp) * HW + (y0 + p_y) * WW + x0;
            #pragma unroll
            for (int it = 0; it < 2; ++it) {
                const int xq = (p_qb + (it << 2)) << 2;
                rlo[it] = *(const float4*)(sp + xq);
                rhi[it] = *(const float4*)(sp + xq + HW);
            }
        }
    };

    auto commit = [&]() {
        if (tid < 384) {
            #pragma unroll
            for (int it = 0; it < 3; ++it) {
                const int row = n_rb + (it << 2);
                unsigned* d = shraw + NOFF + row * NRS + (n_q << 2) * STR + n_cp;
                d[0 * STR] = as_u32(pk(rlo[it].x, rhi[it].x));
                d[1 * STR] = as_u32(pk(rlo[it].y, rhi[it].y));
                d[2 * STR] = as_u32(pk(rlo[it].z, rhi[it].z));
                d[3 * STR] = as_u32(pk(rlo[it].w, rhi[it].w));
            }
        } else {
            #pragma unroll
            for (int it = 0; it < 2; ++it) {
                const int xq = (p_qb + (it << 2)) << 2;
                unsigned* d = shraw + POFF + p_y * PRS + xq * STR + p_cp;
                d[0 * STR] = as_u32(pk(rlo[it].x, rhi[it].x));
                d[1 * STR] = as_u32(pk(rlo[it].y, rhi[it].y));
                d[2 * STR] = as_u32(pk(rlo[it].z, rhi[it].z));
                d[3 * STR] = as_u32(pk(rlo[it].w, rhi[it].w));
            }
        }
    };

    f32x4 acc0[ND], acc1[ND];
    #pragma unroll
    for (int dy = 0; dy < ND; ++dy) {
        acc0[dy] = (f32x4){0.f, 0.f, 0.f, 0.f};
        acc1[dy] = (f32x4){0.f, 0.f, 0.f, 0.f};
    }

    auto compute = [&]() {
        const unsigned* L = shraw;
        const h4 a0 = as_h4(*(const uint2*)(L + POFF + (2 * y2 + 0) * PRS + ((s << 4) + li) * STR + koff));
        const h4 a1 = as_h4(*(const uint2*)(L + POFF + (2 * y2 + 1) * PRS + ((s << 4) + li) * STR + koff));
        const unsigned* NB = L + NOFF + ((ts << 4) + li) * STR + koff;
        h4 bprev = as_h4(*(const uint2*)(NB + (2 * y2) * NRS));
        #pragma unroll
        for (int dy = 0; dy < ND; ++dy) {
            const h4 bnext = as_h4(*(const uint2*)(NB + (2 * y2 + dy + 1) * NRS));
            acc0[dy] = __builtin_amdgcn_mfma_f32_16x16x16f16(a0, bprev, acc0[dy], 0, 0, 0);
            acc1[dy] = __builtin_amdgcn_mfma_f32_16x16x16f16(a1, bnext, acc1[dy], 0, 0, 0);
            bprev = bnext;
        }
    };

    // ---- pipelined chunk loop (T14: issue early, commit late) ----
    issue(0);
    commit();
    __syncthreads();
    for (int ck = 0; ck < 8; ++ck) {
        if (ck < 7) issue(ck + 1);      // loads in flight during compute
        compute();
        __syncthreads();                // all reads of buffer done
        if (ck < 7) {
            commit();                   // vmcnt wait lands here, post-compute
            __syncthreads();            // writes visible for next compute
        }
    }

    // ---- epilogue: scatter -> LDS, then coalesced float4 stores (R10) ----
    float* Ol = (float*)shraw;
    const float invc = 1.0f / (float)CC;
    #pragma unroll
    for (int dy = 0; dy < ND; ++dy) {
        #pragma unroll
        for (int r = 0; r < 4; ++r) {
            const int m  = (kg << 2) + r;
            const int px = (s << 4) + m;
            const int dx = (g << 4) + li - m - SR;
            if ((unsigned)dx < 9u) {
                const int comb = dy * ND + dx;
                Ol[((comb << 2) + (y2 << 1) + 0) * XT + px] = acc0[dy][r] * invc;
                Ol[((comb << 2) + (y2 << 1) + 1) * XT + px] = acc1[dy][r] * invc;
            }
        }
    }
    __syncthreads();
    #pragma unroll
    for (int it = 0; it < 6; ++it) {
        const int c = tid + (it << 9);
        if (c < (81 * YT * XT) / 4) {          // 2592 float4 chunks
            const int px4  = c & 7;
            const int y    = (c >> 3) & 3;
            const int comb = c >> 5;
            const float4 v = *(const float4*)&Ol[c << 2];
            *(float4*)(out + ((size_t)(b * 81 + comb) * HH + (y0 + y)) * WW + x0 + (px4 << 2)) = v;
        }
    }
}

extern "C" void kernel_launch(void* const* d_in, const int* in_sizes, int n_in,
                              void* d_out, int out_size, void* d_ws, size_t ws_size,
                              hipStream_t stream) {
    const float* prv = (const float*)d_in[0];
    const float* nxt = (const float*)d_in[1];
    float* out = (float*)d_out;

    const int nblocks = BB * (HH / YT) * (WW / XT);  // 4 * 32 * 8 = 1024
    costvol_kernel<<<nblocks, 512, 0, stream>>>(prv, nxt, out);
}